// Round 1
// baseline (1181.590 us; speedup 1.0000x reference)
//
#include <hip/hip_runtime.h>
#include <hip/hip_bf16.h>

#define BB 4
#define TT 4096
#define HH 2048
#define NHH 16
#define VOC 100000
#define EE 1024
#define GG 4
#define BT (BB*TT)          // 16384 tokens, p = b*TT + t
#define NKEY (GG*HH)        // 8192
#define NTOT (NKEY+HH)      // 10240

static constexpr float EPS_RMS = 1.1920929e-07f;
static constexpr float EPS_SC  = 1e-5f;
static constexpr float INV_SQRT_H = 0.02209708691207961f; // 1/sqrt(2048)

using f32x4 = __attribute__((ext_vector_type(4))) float;
using s8v   = __attribute__((ext_vector_type(8))) short;
using gvoid = __attribute__((address_space(1))) const void;
using lvoid = __attribute__((address_space(3))) void;

__device__ __forceinline__ unsigned short f2bf(float f){
  union { __hip_bfloat16 h; unsigned short u; } cv;
  cv.h = __float2bfloat16(f);
  return cv.u;
}

// ---------------- weight convert: [keyW | valueW] -> bf16 [10240,1024] ----------------
__global__ __launch_bounds__(256) void convw_kern(const float* __restrict__ kW,
    const float* __restrict__ vW, unsigned short* __restrict__ Wc){
  const long idx  = (long)blockIdx.x*256 + threadIdx.x;
  const long base = idx*4;
  const long KN   = (long)NKEY*EE;
  float4 v;
  if (base < KN) v = *(const float4*)(kW + base);
  else           v = *(const float4*)(vW + (base - KN));
  ushort4 o; o.x=f2bf(v.x); o.y=f2bf(v.y); o.z=f2bf(v.z); o.w=f2bf(v.w);
  *(ushort4*)(Wc + base) = o;
}

// ---------------- hashed gather -> emb bf16 [BT,1024] ----------------
__global__ __launch_bounds__(256) void gather_kern(const int* __restrict__ hids,
    const float* __restrict__ table, unsigned short* __restrict__ emb){
  const int p = blockIdx.x, tid = threadIdx.x;
  const int e = tid*4, head = e>>6, d = e&63;
  const long row = (long)hids[p*NHH + head] + (long)head*VOC;
  const float4 v = *(const float4*)(table + row*64 + d);
  ushort4 o; o.x=f2bf(v.x); o.y=f2bf(v.y); o.z=f2bf(v.z); o.w=f2bf(v.w);
  *(ushort4*)(emb + (size_t)p*EE + e) = o;
}

// ---------------- rq[p] = rsqrt(mean(hs^2)+eps) ----------------
__global__ __launch_bounds__(256) void rq_kern(const float* __restrict__ hs,
                                               float* __restrict__ rq){
  const int p = blockIdx.x, b = p>>12, t = p&4095;
  const float* row = hs + ((size_t)t*BB + b)*HH;
  const int e = threadIdx.x*8;
  float4 v0 = *(const float4*)(row+e);
  float4 v1 = *(const float4*)(row+e+4);
  float s = v0.x*v0.x+v0.y*v0.y+v0.z*v0.z+v0.w*v0.w
          + v1.x*v1.x+v1.y*v1.y+v1.z*v1.z+v1.w*v1.w;
  #pragma unroll
  for (int o=32;o>=1;o>>=1) s += __shfl_xor(s,o);
  __shared__ float red[4];
  if ((threadIdx.x&63)==0) red[threadIdx.x>>6] = s;
  __syncthreads();
  if (threadIdx.x==0){
    float tot = red[0]+red[1]+red[2]+red[3];
    rq[p] = rsqrtf(tot*(1.0f/HH) + EPS_RMS);
  }
}

// ---------------- fused GEMM: C = emb * Wc^T (+bias), epilogue reductions ----------------
// keys cols (n<8192): accumulate sumsq[p,g] += k^2 ; dot[p,g] += k*n1*n2*hs[p,h]
// value cols:        vlin[p,h] = v ; vsq[p] += v^2
__global__ __launch_bounds__(256) void gemm_fused(
    const unsigned short* __restrict__ A, const unsigned short* __restrict__ Bw,
    const float* __restrict__ key_b, const float* __restrict__ value_b,
    const float* __restrict__ n1w, const float* __restrict__ n2w,
    const float* __restrict__ hs, float* __restrict__ vlin,
    float* __restrict__ sumsq, float* __restrict__ dotacc, float* __restrict__ vsq)
{
  __shared__ unsigned short lA[128*64];
  __shared__ unsigned short lB[128*64];
  const int tid = threadIdx.x, w = tid>>6, l = tid&63;
  const int wm = w>>1, wn = w&1;
  const int lg = l&15, lr = l>>4;
  const int tM = blockIdx.y, tN = blockIdx.x;
  const long arow0 = (long)tM*128, brow0 = (long)tN*128;

  f32x4 acc[4][4] = {};

  // staging: instr i covers tile rows 8i..8i+7; lane l -> row 8i+(l>>3), chunk l&7
  // chunk-swizzle: LDS stays linear, global source chunk = (l&7) ^ (row&7)
  const int sub = l>>3;                  // row-within-8 == row&7
  const int schunk = (l&7) ^ sub;
  for (int k0=0; k0<EE; k0+=64){
    #pragma unroll
    for (int j=0;j<4;j++){
      const int i = w*4+j;
      const int r = i*8 + sub;
      const unsigned short* sa = A  + ((arow0 + r)*EE + k0 + schunk*8);
      const unsigned short* sb = Bw + ((brow0 + r)*EE + k0 + schunk*8);
      __builtin_amdgcn_global_load_lds((gvoid*)sa, (lvoid*)(lA + i*512), 16, 0, 0);
      __builtin_amdgcn_global_load_lds((gvoid*)sb, (lvoid*)(lB + i*512), 16, 0, 0);
    }
    __syncthreads();
    #pragma unroll
    for (int kk=0; kk<2; kk++){
      s8v af[4], bfv[4];
      #pragma unroll
      for (int mf=0; mf<4; mf++){
        const int row = wm*64 + mf*16 + lg;
        const int c = (kk*4 + lr) ^ (row&7);
        af[mf] = *(const s8v*)(lA + row*64 + c*8);
      }
      #pragma unroll
      for (int nf=0; nf<4; nf++){
        const int row = wn*64 + nf*16 + lg;
        const int c = (kk*4 + lr) ^ (row&7);
        bfv[nf] = *(const s8v*)(lB + row*64 + c*8);
      }
      #pragma unroll
      for (int mf=0; mf<4; mf++)
        #pragma unroll
        for (int nf=0; nf<4; nf++)
          acc[mf][nf] = __builtin_amdgcn_mfma_f32_16x16x32_bf16(af[mf], bfv[nf], acc[mf][nf], 0,0,0);
    }
    __syncthreads();
  }

  // ---- epilogue ----
  const bool isK = (brow0 < NKEY);
  float bias[4], cw[4]; int ncol[4];
  #pragma unroll
  for (int nf=0; nf<4; nf++){
    const int n = (int)brow0 + wn*64 + nf*16 + lg;
    ncol[nf] = n;
    if (isK){ bias[nf] = key_b[n]; cw[nf] = n1w[n]*n2w[n]; }
    else    { bias[nf] = value_b[n-NKEY]; cw[nf] = 0.f; }
  }
  if (isK){
    const int g = (int)(brow0 >> 11);
    #pragma unroll
    for (int mf=0; mf<4; mf++){
      #pragma unroll
      for (int r=0; r<4; r++){
        const int p = (int)arow0 + wm*64 + mf*16 + lr*4 + r;
        const int b = p >> 12, t = p & 4095;
        const float* hrow = hs + ((size_t)t*BB + b)*HH;
        float ssq=0.f, dt=0.f;
        #pragma unroll
        for (int nf=0; nf<4; nf++){
          const float c = acc[mf][nf][r] + bias[nf];
          ssq += c*c;
          dt  += c * cw[nf] * hrow[ncol[nf] & (HH-1)];
        }
        #pragma unroll
        for (int o=1;o<16;o<<=1){ ssq += __shfl_xor(ssq,o); dt += __shfl_xor(dt,o); }
        if (lg==0){ atomicAdd(&sumsq[p*GG+g], ssq); atomicAdd(&dotacc[p*GG+g], dt); }
      }
    }
  } else {
    #pragma unroll
    for (int mf=0; mf<4; mf++){
      #pragma unroll
      for (int r=0; r<4; r++){
        const int p = (int)arow0 + wm*64 + mf*16 + lr*4 + r;
        float ssq=0.f;
        #pragma unroll
        for (int nf=0; nf<4; nf++){
          const float c = acc[mf][nf][r] + bias[nf];
          ssq += c*c;
          vlin[(size_t)p*HH + (ncol[nf]-NKEY)] = c;
        }
        #pragma unroll
        for (int o=1;o<16;o<<=1){ ssq += __shfl_xor(ssq,o); }
        if (lg==0){ atomicAdd(&vsq[p], ssq); }
      }
    }
  }
}

// ---------------- per-(token,group) scalars: gate + xn-scale a ----------------
__global__ __launch_bounds__(256) void scal_kern(const float* __restrict__ sumsq,
    const float* __restrict__ dotacc, const float* __restrict__ vsq,
    const float* __restrict__ rq, float* __restrict__ gate, float* __restrict__ av){
  const int i = blockIdx.x*256 + threadIdx.x;   // BT*GG
  const int p = i>>2;
  const float rk = rsqrtf(sumsq[i]*(1.0f/HH) + EPS_RMS);
  const float gv = rk * rq[p] * dotacc[i] * INV_SQRT_H;
  const float sgn = (gv>0.f)?1.f:((gv<0.f)?-1.f:0.f);
  const float g1 = sqrtf(fmaxf(fabsf(gv),1e-6f))*sgn;
  const float gt = 1.f/(1.f+__expf(-g1));
  const float msvl = vsq[p]*(1.0f/HH);
  const float a = gt * rsqrtf(gt*gt*msvl + EPS_SC);
  gate[i]=gt; av[i]=a;
}

// ---------------- causal dilated conv + SiLU + mean over G ----------------
// xn[p,g,h] = av[p,g]*vlin[p,h]*scw[g,h]; y = conv(xn); out = 0.25*sum_g(gate*vl + silu(y))
__global__ __launch_bounds__(256) void conv_final(const float* __restrict__ vlin,
    const float* __restrict__ gate, const float* __restrict__ av,
    const float* __restrict__ conv_w, const float* __restrict__ scw,
    float* __restrict__ out){
  const long idx = (long)blockIdx.x*256 + threadIdx.x; // BT*HH
  const int p = (int)(idx >> 11), h = (int)(idx & (HH-1));
  const int b = p >> 12, t = p & 4095;
  float vl[4]; int pt[4];
  #pragma unroll
  for (int k=0;k<4;k++){
    const int tk = t - (3-k)*3;
    pt[k] = (b<<12) | (tk & 4095);
    vl[k] = (tk>=0) ? vlin[(size_t)pt[k]*HH + h] : 0.f;
  }
  float acc = 0.f;
  #pragma unroll
  for (int g=0; g<4; g++){
    const int c = g*HH + h;
    const float4 wv = *(const float4*)(conv_w + (size_t)c*4);
    const float w4[4] = {wv.x, wv.y, wv.z, wv.w};
    float y = 0.f;
    #pragma unroll
    for (int k=0;k<4;k++){
      if (t - (3-k)*3 >= 0) y += w4[k]*av[pt[k]*4+g]*vl[k];
    }
    y *= scw[c];
    const float sy = y * (1.f/(1.f+__expf(-y)));   // SiLU
    acc += gate[p*4+g]*vl[3] + sy;
  }
  out[((size_t)t*BB + b)*HH + h] = 0.25f*acc;
}

extern "C" void kernel_launch(void* const* d_in, const int* in_sizes, int n_in,
                              void* d_out, int out_size, void* d_ws, size_t ws_size,
                              hipStream_t stream){
  (void)in_sizes; (void)n_in; (void)out_size; (void)ws_size;
  const float* hs    = (const float*)d_in[0];
  const int*   hids  = (const int*)d_in[1];
  const float* table = (const float*)d_in[2];
  const float* keyW  = (const float*)d_in[3];
  const float* keyB  = (const float*)d_in[4];
  const float* valW  = (const float*)d_in[5];
  const float* valB  = (const float*)d_in[6];
  const float* n1w   = (const float*)d_in[7];
  const float* n2w   = (const float*)d_in[8];
  const float* scw   = (const float*)d_in[9];
  const float* convw = (const float*)d_in[10];
  float* out = (float*)d_out;

  char* ws = (char*)d_ws;
  size_t off = 0;
  unsigned short* emb = (unsigned short*)(ws+off); off += (size_t)BT*EE*2;     // 33.5 MB
  unsigned short* Wc  = (unsigned short*)(ws+off); off += (size_t)NTOT*EE*2;   // 21 MB
  float* vlin  = (float*)(ws+off); off += (size_t)BT*HH*4;                     // 134 MB
  float* sumsq = (float*)(ws+off); off += (size_t)BT*GG*4;
  float* dotac = (float*)(ws+off); off += (size_t)BT*GG*4;
  float* vsq   = (float*)(ws+off); off += (size_t)BT*4;
  float* rq    = (float*)(ws+off); off += (size_t)BT*4;
  float* gate  = (float*)(ws+off); off += (size_t)BT*GG*4;
  float* av    = (float*)(ws+off); off += (size_t)BT*GG*4;

  // zero the atomic accumulators (sumsq, dotac, vsq are contiguous)
  (void)hipMemsetAsync(sumsq, 0, (size_t)(BT*GG*2 + BT)*4, stream);

  convw_kern<<<(NTOT*EE/4)/256, 256, 0, stream>>>(keyW, valW, Wc);
  gather_kern<<<BT, 256, 0, stream>>>(hids, table, emb);
  rq_kern<<<BT, 256, 0, stream>>>(hs, rq);
  dim3 gg(NTOT/128, BT/128);
  gemm_fused<<<gg, 256, 0, stream>>>(emb, Wc, keyB, valB, n1w, n2w, hs, vlin, sumsq, dotac, vsq);
  scal_kern<<<(BT*GG)/256, 256, 0, stream>>>(sumsq, dotac, vsq, rq, gate, av);
  conv_final<<<((size_t)BT*HH)/256, 256, 0, stream>>>(vlin, gate, av, convw, scw, out);
}

// Round 2
// 1073.642 us; speedup vs baseline: 1.1005x; 1.1005x over previous
//
#include <hip/hip_runtime.h>
#include <hip/hip_bf16.h>

#define BB 4
#define TT 4096
#define HH 2048
#define NHH 16
#define VOC 100000
#define EE 1024
#define GG 4
#define BT (BB*TT)          // 16384 tokens, p = b*TT + t
#define NKEY (GG*HH)        // 8192
#define NTOT (NKEY+HH)      // 10240
#define NPART 32            // partial slots per (p,g): 16 colblocks x 2 waves

static constexpr float EPS_RMS = 1.1920929e-07f;
static constexpr float EPS_SC  = 1e-5f;
static constexpr float INV_SQRT_H = 0.02209708691207961f; // 1/sqrt(2048)

using f32x4 = __attribute__((ext_vector_type(4))) float;
using s8v   = __attribute__((ext_vector_type(8))) short;
using gvoid = __attribute__((address_space(1))) const void;
using lvoid = __attribute__((address_space(3))) void;

__device__ __forceinline__ unsigned short f2bf(float f){
  union { __hip_bfloat16 h; unsigned short u; } cv;
  cv.h = __float2bfloat16(f);
  return cv.u;
}
__device__ __forceinline__ float bf2f(unsigned short u){
  union { float f; unsigned u; } cv;
  cv.u = ((unsigned)u) << 16;
  return cv.f;
}

// ---------------- weight convert: [keyW | valueW] -> bf16 [10240,1024] ----------------
__global__ __launch_bounds__(256) void convw_kern(const float* __restrict__ kW,
    const float* __restrict__ vW, unsigned short* __restrict__ Wc){
  const long idx  = (long)blockIdx.x*256 + threadIdx.x;
  const long base = idx*4;
  const long KN   = (long)NKEY*EE;
  float4 v;
  if (base < KN) v = *(const float4*)(kW + base);
  else           v = *(const float4*)(vW + (base - KN));
  ushort4 o; o.x=f2bf(v.x); o.y=f2bf(v.y); o.z=f2bf(v.z); o.w=f2bf(v.w);
  *(ushort4*)(Wc + base) = o;
}

// ---------------- hashed gather -> emb bf16 [BT,1024] ----------------
__global__ __launch_bounds__(256) void gather_kern(const int* __restrict__ hids,
    const float* __restrict__ table, unsigned short* __restrict__ emb){
  const int p = blockIdx.x, tid = threadIdx.x;
  const int e = tid*4, head = e>>6, d = e&63;
  const long row = (long)hids[p*NHH + head] + (long)head*VOC;
  const float4 v = *(const float4*)(table + row*64 + d);
  ushort4 o; o.x=f2bf(v.x); o.y=f2bf(v.y); o.z=f2bf(v.z); o.w=f2bf(v.w);
  *(ushort4*)(emb + (size_t)p*EE + e) = o;
}

// ---------------- rq[p] = rsqrt(mean(hs^2)+eps) ----------------
__global__ __launch_bounds__(256) void rq_kern(const float* __restrict__ hs,
                                               float* __restrict__ rq){
  const int p = blockIdx.x, b = p>>12, t = p&4095;
  const float* row = hs + ((size_t)t*BB + b)*HH;
  const int e = threadIdx.x*8;
  float4 v0 = *(const float4*)(row+e);
  float4 v1 = *(const float4*)(row+e+4);
  float s = v0.x*v0.x+v0.y*v0.y+v0.z*v0.z+v0.w*v0.w
          + v1.x*v1.x+v1.y*v1.y+v1.z*v1.z+v1.w*v1.w;
  #pragma unroll
  for (int o=32;o>=1;o>>=1) s += __shfl_xor(s,o);
  __shared__ float red[4];
  if ((threadIdx.x&63)==0) red[threadIdx.x>>6] = s;
  __syncthreads();
  if (threadIdx.x==0){
    float tot = red[0]+red[1]+red[2]+red[3];
    rq[p] = rsqrtf(tot*(1.0f/HH) + EPS_RMS);
  }
}

// ---------------- fused GEMM: C = emb * Wc^T (+bias), double-buffered prefetch ----------------
// keys cols (n<8192): sumsqp/dotp partials per (p,g,colblock,wave)
// value cols:        vlinb[p,h] = bf16(v) ; vsqp partials per (p,colblock,wave)
__global__ __launch_bounds__(256) void gemm_fused(
    const unsigned short* __restrict__ A, const unsigned short* __restrict__ Bw,
    const float* __restrict__ key_b, const float* __restrict__ value_b,
    const float* __restrict__ n1w, const float* __restrict__ n2w,
    const float* __restrict__ hs, unsigned short* __restrict__ vlinb,
    float* __restrict__ sumsqp, float* __restrict__ dotp, float* __restrict__ vsqp)
{
  __shared__ unsigned short sh[32768];   // 64 KB: [2 bufs][A 16KB | B 16KB]
  const int tid = threadIdx.x, w = tid>>6, l = tid&63;
  const int wm = w>>1, wn = w&1;
  const int lg = l&15, lr = l>>4;
  const int tM = blockIdx.y, tN = blockIdx.x;
  const long arow0 = (long)tM*128, brow0 = (long)tN*128;

  f32x4 acc[4][4] = {};

  // staging: instr i covers tile rows 8i..8i+7; lane l -> row 8i+(l>>3), chunk l&7
  // chunk-swizzle: LDS stays linear, global source chunk = (l&7) ^ (row&7)
  const int sub = l>>3;
  const int schunk = (l&7) ^ sub;
  size_t aoff[4], boff[4];
  #pragma unroll
  for (int j=0;j<4;j++){
    const int r = (w*4+j)*8 + sub;
    aoff[j] = (size_t)(arow0 + r)*EE + schunk*8;
    boff[j] = (size_t)(brow0 + r)*EE + schunk*8;
  }

#define STAGE(c, k0) { \
    unsigned short* pA_ = sh + (c)*16384; \
    unsigned short* pB_ = pA_ + 8192; \
    _Pragma("unroll") \
    for (int j=0;j<4;j++){ \
      const int i_ = w*4+j; \
      __builtin_amdgcn_global_load_lds((gvoid*)(A + aoff[j] + (k0)), (lvoid*)(pA_ + i_*512), 16, 0, 0); \
      __builtin_amdgcn_global_load_lds((gvoid*)(Bw + boff[j] + (k0)), (lvoid*)(pB_ + i_*512), 16, 0, 0); \
    } }

#define COMPUTE(c) { \
    const unsigned short* pA_ = sh + (c)*16384; \
    const unsigned short* pB_ = pA_ + 8192; \
    _Pragma("unroll") \
    for (int kk=0;kk<2;kk++){ \
      s8v af[4], bfv[4]; \
      _Pragma("unroll") \
      for (int mf=0; mf<4; mf++){ \
        const int row_ = wm*64 + mf*16 + lg; \
        const int cc_ = (kk*4 + lr) ^ (row_&7); \
        af[mf] = *(const s8v*)(pA_ + row_*64 + cc_*8); \
      } \
      _Pragma("unroll") \
      for (int nf=0; nf<4; nf++){ \
        const int row_ = wn*64 + nf*16 + lg; \
        const int cc_ = (kk*4 + lr) ^ (row_&7); \
        bfv[nf] = *(const s8v*)(pB_ + row_*64 + cc_*8); \
      } \
      _Pragma("unroll") \
      for (int mf=0; mf<4; mf++) \
        _Pragma("unroll") \
        for (int nf=0; nf<4; nf++) \
          acc[mf][nf] = __builtin_amdgcn_mfma_f32_16x16x32_bf16(af[mf], bfv[nf], acc[mf][nf], 0,0,0); \
    } }

  // prologue: stage tile 0, wait
  STAGE(0, 0);
  __syncthreads();
  // main loop: 16 K-tiles of 64, processed in pairs with static buffer indices.
  // STAGE(next) issued BEFORE compute so the vmcnt(0)-at-barrier drain is hidden
  // under the ds_read+MFMA work of the current tile.
  for (int kt=0; kt<16; kt+=2){
    STAGE(1, (kt+1)*64);
    COMPUTE(0);
    __syncthreads();
    if (kt+2 < 16) STAGE(0, (kt+2)*64);
    COMPUTE(1);
    __syncthreads();
  }
#undef STAGE
#undef COMPUTE

  // ---- epilogue ----
  const bool isK = (brow0 < NKEY);
  float bias[4], cw[4];
  #pragma unroll
  for (int nf=0; nf<4; nf++){
    const int n = (int)brow0 + wn*64 + nf*16 + lg;
    if (isK){ bias[nf] = key_b[n]; cw[nf] = n1w[n]*n2w[n]; }
    else    { bias[nf] = value_b[n-NKEY]; cw[nf] = 0.f; }
  }

  if (isK){
    // stage hs tile [128 p-rows][128 cols] into LDS (reuse GEMM LDS), XOR-swizzled
    float* hsT = (float*)sh;
    const int col0 = (int)(brow0 & (HH-1));
    #pragma unroll
    for (int pass=0; pass<16; pass++){
      const int rl = pass*8 + (tid>>5);
      const int c4 = (tid&31)*4;
      const int p = (int)arow0 + rl; const int b = p>>12, t = p&4095;
      const float4 v = *(const float4*)(hs + ((size_t)t*BB+b)*HH + col0 + c4);
      const int cs = c4 ^ (((rl>>2)&3)<<4);
      *(float4*)(hsT + rl*128 + cs) = v;
    }
    __syncthreads();
    const int g = (int)(brow0 >> 11);
    const int xb2 = ((tN & 15)<<1) | wn;
    #pragma unroll
    for (int mf=0; mf<4; mf++){
      #pragma unroll
      for (int r=0; r<4; r++){
        const int rowl = wm*64 + mf*16 + lr*4 + r;
        const int p = (int)arow0 + rowl;
        const int sw = ((rowl>>2)&3)<<4;
        float ssq=0.f, dt=0.f;
        #pragma unroll
        for (int nf=0; nf<4; nf++){
          const float c = acc[mf][nf][r] + bias[nf];
          const int coll = wn*64 + nf*16 + lg;
          ssq += c*c;
          dt  += c * cw[nf] * hsT[rowl*128 + (coll ^ sw)];
        }
        #pragma unroll
        for (int o=1;o<16;o<<=1){ ssq += __shfl_xor(ssq,o); dt += __shfl_xor(dt,o); }
        if (lg==0){
          sumsqp[(size_t)(p*GG+g)*NPART + xb2] = ssq;
          dotp  [(size_t)(p*GG+g)*NPART + xb2] = dt;
        }
      }
    }
  } else {
    const int xb2 = (((tN-64) & 15)<<1) | wn;
    #pragma unroll
    for (int mf=0; mf<4; mf++){
      #pragma unroll
      for (int r=0; r<4; r++){
        const int p = (int)arow0 + wm*64 + mf*16 + lr*4 + r;
        float ssq=0.f;
        #pragma unroll
        for (int nf=0; nf<4; nf++){
          const float c = acc[mf][nf][r] + bias[nf];
          const int n = wn*64 + nf*16 + lg;
          vlinb[(size_t)p*HH + (int)(brow0-NKEY) + n] = f2bf(c);
          ssq += c*c;
        }
        #pragma unroll
        for (int o=1;o<16;o<<=1){ ssq += __shfl_xor(ssq,o); }
        if (lg==0) vsqp[(size_t)p*NPART + xb2] = ssq;
      }
    }
  }
}

// ---------------- per-(token,group) scalars: gate + xn-scale a ----------------
__global__ __launch_bounds__(256) void scal_kern(const float* __restrict__ sumsqp,
    const float* __restrict__ dotp, const float* __restrict__ vsqp,
    const float* __restrict__ rq, float* __restrict__ gate, float* __restrict__ av){
  const int i = blockIdx.x*256 + threadIdx.x;   // BT*GG
  const int p = i>>2;
  float ss=0.f, dd=0.f, vv=0.f;
  #pragma unroll
  for (int j=0;j<NPART;j++){ ss += sumsqp[(size_t)i*NPART+j]; dd += dotp[(size_t)i*NPART+j]; }
  #pragma unroll
  for (int j=0;j<NPART;j++){ vv += vsqp[(size_t)p*NPART+j]; }
  const float rk = rsqrtf(ss*(1.0f/HH) + EPS_RMS);
  const float gv = rk * rq[p] * dd * INV_SQRT_H;
  const float sgn = (gv>0.f)?1.f:((gv<0.f)?-1.f:0.f);
  const float g1 = sqrtf(fmaxf(fabsf(gv),1e-6f))*sgn;
  const float gt = 1.f/(1.f+__expf(-g1));
  const float msvl = vv*(1.0f/HH);
  const float a = gt * rsqrtf(gt*gt*msvl + EPS_SC);
  gate[i]=gt; av[i]=a;
}

// ---------------- causal dilated conv + SiLU + mean over G ----------------
__global__ __launch_bounds__(256) void conv_final(const unsigned short* __restrict__ vlinb,
    const float* __restrict__ gate, const float* __restrict__ av,
    const float* __restrict__ conv_w, const float* __restrict__ scw,
    float* __restrict__ out){
  const long idx = (long)blockIdx.x*256 + threadIdx.x; // BT*HH
  const int p = (int)(idx >> 11), h = (int)(idx & (HH-1));
  const int b = p >> 12, t = p & 4095;
  float vl[4]; int pt[4];
  #pragma unroll
  for (int k=0;k<4;k++){
    const int tk = t - (3-k)*3;
    pt[k] = (b<<12) | (tk & 4095);
    vl[k] = (tk>=0) ? bf2f(vlinb[(size_t)pt[k]*HH + h]) : 0.f;
  }
  float acc = 0.f;
  #pragma unroll
  for (int g=0; g<4; g++){
    const int c = g*HH + h;
    const float4 wv = *(const float4*)(conv_w + (size_t)c*4);
    const float w4[4] = {wv.x, wv.y, wv.z, wv.w};
    float y = 0.f;
    #pragma unroll
    for (int k=0;k<4;k++){
      if (t - (3-k)*3 >= 0) y += w4[k]*av[pt[k]*4+g]*vl[k];
    }
    y *= scw[c];
    const float sy = y * (1.f/(1.f+__expf(-y)));   // SiLU
    acc += gate[p*4+g]*vl[3] + sy;
  }
  out[((size_t)t*BB + b)*HH + h] = 0.25f*acc;
}

extern "C" void kernel_launch(void* const* d_in, const int* in_sizes, int n_in,
                              void* d_out, int out_size, void* d_ws, size_t ws_size,
                              hipStream_t stream){
  (void)in_sizes; (void)n_in; (void)out_size; (void)ws_size;
  const float* hs    = (const float*)d_in[0];
  const int*   hids  = (const int*)d_in[1];
  const float* table = (const float*)d_in[2];
  const float* keyW  = (const float*)d_in[3];
  const float* keyB  = (const float*)d_in[4];
  const float* valW  = (const float*)d_in[5];
  const float* valB  = (const float*)d_in[6];
  const float* n1w   = (const float*)d_in[7];
  const float* n2w   = (const float*)d_in[8];
  const float* scw   = (const float*)d_in[9];
  const float* convw = (const float*)d_in[10];
  float* out = (float*)d_out;

  char* ws = (char*)d_ws;
  size_t off = 0;
  unsigned short* emb   = (unsigned short*)(ws+off); off += (size_t)BT*EE*2;      // 33.5 MB
  unsigned short* Wc    = (unsigned short*)(ws+off); off += (size_t)NTOT*EE*2;    // 21 MB
  unsigned short* vlinb = (unsigned short*)(ws+off); off += (size_t)BT*HH*2;      // 67 MB
  float* sumsqp = (float*)(ws+off); off += (size_t)BT*GG*NPART*4;                 // 8.4 MB
  float* dotp   = (float*)(ws+off); off += (size_t)BT*GG*NPART*4;                 // 8.4 MB
  float* vsqp   = (float*)(ws+off); off += (size_t)BT*NPART*4;                    // 2.1 MB
  float* rq     = (float*)(ws+off); off += (size_t)BT*4;
  float* gate   = (float*)(ws+off); off += (size_t)BT*GG*4;
  float* av     = (float*)(ws+off); off += (size_t)BT*GG*4;

  convw_kern<<<(NTOT*EE/4)/256, 256, 0, stream>>>(keyW, valW, Wc);
  gather_kern<<<BT, 256, 0, stream>>>(hids, table, emb);
  rq_kern<<<BT, 256, 0, stream>>>(hs, rq);
  dim3 gg(NTOT/128, BT/128);
  gemm_fused<<<gg, 256, 0, stream>>>(emb, Wc, keyB, valB, n1w, n2w, hs, vlinb, sumsqp, dotp, vsqp);
  scal_kern<<<(BT*GG)/256, 256, 0, stream>>>(sumsqp, dotp, vsqp, rq, gate, av);
  conv_final<<<((size_t)BT*HH)/256, 256, 0, stream>>>(vlinb, gate, av, convw, scw, out);
}

// Round 3
// 780.398 us; speedup vs baseline: 1.5141x; 1.3758x over previous
//
#include <hip/hip_runtime.h>
#include <hip/hip_bf16.h>

#define BB 4
#define TT 4096
#define HH 2048
#define NHH 16
#define VOC 100000
#define EE 1024
#define GG 4
#define BT (BB*TT)          // 16384 tokens, p = b*TT + t
#define NKEY (GG*HH)        // 8192
#define NTOT (NKEY+HH)      // 10240
#define NPART 32

static constexpr float EPS_RMS = 1.1920929e-07f;
static constexpr float EPS_SC  = 1e-5f;
static constexpr float INV_SQRT_H = 0.02209708691207961f; // 1/sqrt(2048)

using f32x4 = __attribute__((ext_vector_type(4))) float;
using s8v   = __attribute__((ext_vector_type(8))) short;
using gvoid = __attribute__((address_space(1))) const void;
using lvoid = __attribute__((address_space(3))) void;

__device__ __forceinline__ unsigned short f2bf(float f){
  union { __hip_bfloat16 h; unsigned short u; } cv;
  cv.h = __float2bfloat16(f);
  return cv.u;
}
__device__ __forceinline__ float bf2f(unsigned short u){
  union { float f; unsigned u; } cv;
  cv.u = ((unsigned)u) << 16;
  return cv.f;
}

// ---------------- weight convert: [keyW | valueW] -> bf16 [10240,1024] ----------------
__global__ __launch_bounds__(256) void convw_kern(const float* __restrict__ kW,
    const float* __restrict__ vW, unsigned short* __restrict__ Wc){
  const long idx  = (long)blockIdx.x*256 + threadIdx.x;
  const long base = idx*4;
  const long KN   = (long)NKEY*EE;
  float4 v;
  if (base < KN) v = *(const float4*)(kW + base);
  else           v = *(const float4*)(vW + (base - KN));
  ushort4 o; o.x=f2bf(v.x); o.y=f2bf(v.y); o.z=f2bf(v.z); o.w=f2bf(v.w);
  *(ushort4*)(Wc + base) = o;
}

// ---------------- hashed gather -> emb bf16 [BT,1024] ----------------
__global__ __launch_bounds__(256) void gather_kern(const int* __restrict__ hids,
    const float* __restrict__ table, unsigned short* __restrict__ emb){
  const int p = blockIdx.x, tid = threadIdx.x;
  const int e = tid*4, head = e>>6, d = e&63;
  const long row = (long)hids[p*NHH + head] + (long)head*VOC;
  const float4 v = *(const float4*)(table + row*64 + d);
  ushort4 o; o.x=f2bf(v.x); o.y=f2bf(v.y); o.z=f2bf(v.z); o.w=f2bf(v.w);
  *(ushort4*)(emb + (size_t)p*EE + e) = o;
}

// ---------------- rq[p] = rsqrt(mean(hs^2)+eps) ----------------
__global__ __launch_bounds__(256) void rq_kern(const float* __restrict__ hs,
                                               float* __restrict__ rq){
  const int p = blockIdx.x, b = p>>12, t = p&4095;
  const float* row = hs + ((size_t)t*BB + b)*HH;
  const int e = threadIdx.x*8;
  float4 v0 = *(const float4*)(row+e);
  float4 v1 = *(const float4*)(row+e+4);
  float s = v0.x*v0.x+v0.y*v0.y+v0.z*v0.z+v0.w*v0.w
          + v1.x*v1.x+v1.y*v1.y+v1.z*v1.z+v1.w*v1.w;
  #pragma unroll
  for (int o=32;o>=1;o>>=1) s += __shfl_xor(s,o);
  __shared__ float red[4];
  if ((threadIdx.x&63)==0) red[threadIdx.x>>6] = s;
  __syncthreads();
  if (threadIdx.x==0){
    float tot = red[0]+red[1]+red[2]+red[3];
    rq[p] = rsqrtf(tot*(1.0f/HH) + EPS_RMS);
  }
}

// ================= 256x256 8-phase GEMM (T2+T3+T4+T5), fused epilogue =================
__global__ __launch_bounds__(512, 2) void gemm8(
    const unsigned short* __restrict__ A, const unsigned short* __restrict__ Bw,
    const float* __restrict__ key_b, const float* __restrict__ value_b,
    const float* __restrict__ n1w, const float* __restrict__ n2w,
    const float* __restrict__ hs, unsigned short* __restrict__ vlinb,
    float* __restrict__ sumsqp, float* __restrict__ dotp, float* __restrict__ vsqp)
{
  __shared__ unsigned short sh[65536];   // 128 KiB: [2 bufs][A 32KB | B 32KB]
  const int tid = threadIdx.x, w = tid>>6, l = tid&63;
  const int wm = w>>2, wn = w&3;
  const int lg = l&15, lr = l>>4;
  const int tN = blockIdx.x, tM = blockIdx.y;
  const int Mrow0 = tM*256, Nrow0 = tN*256;

  // staging: per half-tile (128 rows x 64 K), wave w, j in {0,1}: rows w*16+j*8 + (l>>3)
  // conflict-free 3-bit chunk swizzle: LDS linear, source chunk = (l&7) ^ (row&7)
  const int lp = l>>3, lcs = (l&7)^lp;
  const size_t aoffT = (size_t)(Mrow0 + w*16 + lp)*EE + lcs*8;
  const size_t boffT = (size_t)(Nrow0 + w*16 + lp)*EE + lcs*8;
  // ds_read: chunk' = (kk*4+lr) ^ (row&7), row&7 == lg&7
  const int c0 = lr ^ (lg&7);
  const unsigned aBase = (unsigned)(wm*8192 + lg*64);
  const unsigned bBase = (unsigned)(16384 + (wn>>1)*8192 + (wn&1)*4096 + lg*64);

  f32x4 acc[8][4] = {};
  s8v aR[2][4], bR[2][4];

#define STAGEH(ISB, H, KT, SB) { \
    const unsigned short* s0_ = ((ISB) ? (Bw + boffT) : (A + aoffT)) + (H)*131072 + (KT)*64; \
    const unsigned d0_ = (SB)*32768 + (ISB)*16384 + (H)*8192 + w*1024; \
    __builtin_amdgcn_global_load_lds((gvoid*)s0_,        (lvoid*)(sh + d0_),       16, 0, 0); \
    __builtin_amdgcn_global_load_lds((gvoid*)(s0_+8192), (lvoid*)(sh + d0_ + 512), 16, 0, 0); \
  }

#define BAR() { asm volatile("" ::: "memory"); __builtin_amdgcn_s_barrier(); asm volatile("" ::: "memory"); }

#define RD_A(CB, KK, MH) { \
    const unsigned short* p_ = sh + (CB)*32768 + aBase; \
    const unsigned ck_ = (unsigned)((c0 ^ ((KK)<<2))<<3); \
    aR[KK][0] = *(const s8v*)(p_ + ((MH)*4+0)*1024 + ck_); \
    aR[KK][1] = *(const s8v*)(p_ + ((MH)*4+1)*1024 + ck_); \
    aR[KK][2] = *(const s8v*)(p_ + ((MH)*4+2)*1024 + ck_); \
    aR[KK][3] = *(const s8v*)(p_ + ((MH)*4+3)*1024 + ck_); }

#define RD_B(CB, KK) { \
    const unsigned short* p_ = sh + (CB)*32768 + bBase; \
    const unsigned ck_ = (unsigned)((c0 ^ ((KK)<<2))<<3); \
    bR[KK][0] = *(const s8v*)(p_ + 0*1024 + ck_); \
    bR[KK][1] = *(const s8v*)(p_ + 1*1024 + ck_); \
    bR[KK][2] = *(const s8v*)(p_ + 2*1024 + ck_); \
    bR[KK][3] = *(const s8v*)(p_ + 3*1024 + ck_); }

#define MM(MH, KK) { \
    __builtin_amdgcn_s_setprio(1); \
    _Pragma("unroll") \
    for (int mf=0; mf<4; mf++) \
      _Pragma("unroll") \
      for (int nf=0; nf<4; nf++) \
        acc[(MH)*4+mf][nf] = __builtin_amdgcn_mfma_f32_16x16x32_bf16(aR[KK][mf], bR[KK][nf], acc[(MH)*4+mf][nf], 0,0,0); \
    __builtin_amdgcn_s_setprio(0); }

// first phase of a K-tile: stage, counted vmcnt, barrier, THEN reads (buffer only valid after bar)
#define PH_FIRST(CB, SB, STKT) { \
    STAGEH(0, 0, STKT, SB); \
    asm volatile("s_waitcnt vmcnt(2)" ::: "memory"); \
    BAR(); \
    RD_A(CB, 0, 0); RD_B(CB, 0); \
    asm volatile("s_waitcnt lgkmcnt(0)" ::: "memory"); \
    __builtin_amdgcn_sched_barrier(0); \
    MM(0, 0); \
    BAR(); }

#define PH_FIRST_LAST(CB) { \
    asm volatile("s_waitcnt vmcnt(0)" ::: "memory"); \
    BAR(); \
    RD_A(CB, 0, 0); RD_B(CB, 0); \
    asm volatile("s_waitcnt lgkmcnt(0)" ::: "memory"); \
    __builtin_amdgcn_sched_barrier(0); \
    MM(0, 0); \
    BAR(); }

// other phases: reads (from already-valid buffer) before barrier, overlap with stage issue
#define PH_REST(CB, SB, MH, KK, RDB, ISB, H, STKT, DOST) { \
    RD_A(CB, KK, MH); \
    if (RDB) RD_B(CB, KK); \
    if (DOST) STAGEH(ISB, H, STKT, SB); \
    BAR(); \
    asm volatile("s_waitcnt lgkmcnt(0)" ::: "memory"); \
    __builtin_amdgcn_sched_barrier(0); \
    MM(MH, KK); \
    BAR(); }

  // prologue: stage K-tile 0 (4 half-tiles) into buf0
  STAGEH(0,0,0,0); STAGEH(0,1,0,0); STAGEH(1,0,0,0); STAGEH(1,1,0,0);

  for (int i=0; i<7; i++){
    const int kN = 2*i+1, kE = 2*i+2;
    PH_FIRST(0, 1, kN);                       // P0: compute kt even q(0,0); stage A-h0 of kt+1
    PH_REST (0, 1, 0,1, true , 0,1, kN, true); // P1: q(0,1); stage A-h1
    PH_REST (0, 1, 1,0, false, 1,0, kN, true); // P2: q(1,0); stage B-h0
    PH_REST (0, 1, 1,1, false, 1,1, kN, true); // P3: q(1,1); stage B-h1
    PH_FIRST(1, 0, kE);                       // P4: compute kt odd; stage A-h0 of kt+2
    PH_REST (1, 0, 0,1, true , 0,1, kE, true);
    PH_REST (1, 0, 1,0, false, 1,0, kE, true);
    PH_REST (1, 0, 1,1, false, 1,1, kE, true);
  }
  // peeled last iteration: compute kt14 (stage kt15), compute kt15 (no stage, vmcnt(0))
  PH_FIRST(0, 1, 15);
  PH_REST (0, 1, 0,1, true , 0,1, 15, true);
  PH_REST (0, 1, 1,0, false, 1,0, 15, true);
  PH_REST (0, 1, 1,1, false, 1,1, 15, true);
  PH_FIRST_LAST(1);
  PH_REST (1, 0, 0,1, true , 0,0, 0, false);
  PH_REST (1, 0, 1,0, false, 0,0, 0, false);
  PH_REST (1, 0, 1,1, false, 0,0, 0, false);

#undef STAGEH
#undef BAR
#undef RD_A
#undef RD_B
#undef MM
#undef PH_FIRST
#undef PH_FIRST_LAST
#undef PH_REST

  // ---- epilogue ----
  const bool isK = (Nrow0 < NKEY);
  float bias[4], cw[4]; int hcol[4];
  #pragma unroll
  for (int nf=0; nf<4; nf++){
    const int n = Nrow0 + wn*64 + nf*16 + lg;
    hcol[nf] = n & (HH-1);
    if (isK){ bias[nf] = key_b[n]; cw[nf] = n1w[n]*n2w[n]; }
    else    { bias[nf] = value_b[n-NKEY]; cw[nf] = 0.f; }
  }

  if (isK){
    const int g = Nrow0 >> 11;
    const int slot = (tN&7)*4 + wn;
    const int pbase = Mrow0 + wm*128;
    #pragma unroll
    for (int mfa=0; mfa<8; mfa++){
      #pragma unroll
      for (int rr=0; rr<4; rr++){
        const int p = pbase + mfa*16 + lr*4 + rr;
        const int b = p>>12, t = p&4095;
        const float* hrow = hs + ((size_t)t*BB + b)*HH;
        float ssq=0.f, dt=0.f;
        #pragma unroll
        for (int nf=0; nf<4; nf++){
          const float c = acc[mfa][nf][rr] + bias[nf];
          ssq += c*c;
          dt  += c * cw[nf] * hrow[hcol[nf]];
        }
        #pragma unroll
        for (int o=1;o<16;o<<=1){ ssq += __shfl_xor(ssq,o); dt += __shfl_xor(dt,o); }
        if (lg==0){
          sumsqp[(size_t)(p*GG+g)*NPART + slot] = ssq;
          dotp  [(size_t)(p*GG+g)*NPART + slot] = dt;
        }
      }
    }
  } else {
    const int slot = (tN-32)*4 + wn;
    const int h0 = Nrow0 - NKEY + wn*64;
    const int pbase = Mrow0 + wm*128;
    #pragma unroll
    for (int mfa=0; mfa<8; mfa++){
      #pragma unroll
      for (int rr=0; rr<4; rr++){
        const int p = pbase + mfa*16 + lr*4 + rr;
        float ssq=0.f;
        #pragma unroll
        for (int nf=0; nf<4; nf++){
          const float c = acc[mfa][nf][rr] + bias[nf];
          vlinb[(size_t)p*HH + h0 + nf*16 + lg] = f2bf(c);
          ssq += c*c;
        }
        #pragma unroll
        for (int o=1;o<16;o<<=1){ ssq += __shfl_xor(ssq,o); }
        if (lg==0) vsqp[(size_t)p*NPART + slot] = ssq;
      }
    }
  }
}

// ---------------- per-(token,group) scalars: gate + xn-scale a ----------------
__global__ __launch_bounds__(256) void scal_kern(const float* __restrict__ sumsqp,
    const float* __restrict__ dotp, const float* __restrict__ vsqp,
    const float* __restrict__ rq, float* __restrict__ gate, float* __restrict__ av){
  const int i = blockIdx.x*256 + threadIdx.x;   // BT*GG
  const int p = i>>2;
  float ss=0.f, dd=0.f, vv=0.f;
  #pragma unroll
  for (int j=0;j<NPART;j++){ ss += sumsqp[(size_t)i*NPART+j]; dd += dotp[(size_t)i*NPART+j]; }
  #pragma unroll
  for (int j=0;j<NPART;j++){ vv += vsqp[(size_t)p*NPART+j]; }
  const float rk = rsqrtf(ss*(1.0f/HH) + EPS_RMS);
  const float gv = rk * rq[p] * dd * INV_SQRT_H;
  const float sgn = (gv>0.f)?1.f:((gv<0.f)?-1.f:0.f);
  const float g1 = sqrtf(fmaxf(fabsf(gv),1e-6f))*sgn;
  const float gt = 1.f/(1.f+__expf(-g1));
  const float msvl = vv*(1.0f/HH);
  const float a = gt * rsqrtf(gt*gt*msvl + EPS_SC);
  gate[i]=gt; av[i]=a;
}

// ---------------- causal dilated conv + SiLU + mean over G (vectorized 8 h/thread) ----------------
__global__ __launch_bounds__(256) void conv_final(const unsigned short* __restrict__ vlinb,
    const float* __restrict__ gate, const float* __restrict__ av,
    const float* __restrict__ conv_w, const float* __restrict__ scw,
    float* __restrict__ out){
  const int p = blockIdx.x, h0 = threadIdx.x*8;
  const int b = p>>12, t = p&4095;
  s8v vl8[4]; float avk[4][4];
  #pragma unroll
  for (int k=0;k<4;k++){
    const int tk = t - (3-k)*3;
    const int ptk = (b<<12) | (tk&4095);
    if (tk >= 0){
      vl8[k] = *(const s8v*)(vlinb + (size_t)ptk*HH + h0);
      #pragma unroll
      for (int g=0; g<4; g++) avk[k][g] = av[ptk*4+g];
    } else {
      s8v z = {0,0,0,0,0,0,0,0}; vl8[k] = z;
      #pragma unroll
      for (int g=0; g<4; g++) avk[k][g] = 0.f;
    }
  }
  float gt[4];
  #pragma unroll
  for (int g=0; g<4; g++) gt[g] = gate[p*4+g];
  float accv[8];
  #pragma unroll
  for (int j=0;j<8;j++) accv[j] = 0.f;
  #pragma unroll
  for (int g=0; g<4; g++){
    #pragma unroll
    for (int j=0;j<8;j++){
      const int c = g*HH + h0 + j;
      const float4 wv = *(const float4*)(conv_w + (size_t)c*4);
      float y = wv.x*avk[0][g]*bf2f((unsigned short)vl8[0][j])
              + wv.y*avk[1][g]*bf2f((unsigned short)vl8[1][j])
              + wv.z*avk[2][g]*bf2f((unsigned short)vl8[2][j])
              + wv.w*avk[3][g]*bf2f((unsigned short)vl8[3][j]);
      y *= scw[c];
      const float sy = y * (1.f/(1.f+__expf(-y)));
      accv[j] += gt[g]*bf2f((unsigned short)vl8[3][j]) + sy;
    }
  }
  float4 o0, o1;
  o0.x=accv[0]*0.25f; o0.y=accv[1]*0.25f; o0.z=accv[2]*0.25f; o0.w=accv[3]*0.25f;
  o1.x=accv[4]*0.25f; o1.y=accv[5]*0.25f; o1.z=accv[6]*0.25f; o1.w=accv[7]*0.25f;
  float* orow = out + ((size_t)t*BB + b)*HH + h0;
  *(float4*)orow = o0;
  *(float4*)(orow+4) = o1;
}

extern "C" void kernel_launch(void* const* d_in, const int* in_sizes, int n_in,
                              void* d_out, int out_size, void* d_ws, size_t ws_size,
                              hipStream_t stream){
  (void)in_sizes; (void)n_in; (void)out_size; (void)ws_size;
  const float* hs    = (const float*)d_in[0];
  const int*   hids  = (const int*)d_in[1];
  const float* table = (const float*)d_in[2];
  const float* keyW  = (const float*)d_in[3];
  const float* keyB  = (const float*)d_in[4];
  const float* valW  = (const float*)d_in[5];
  const float* valB  = (const float*)d_in[6];
  const float* n1w   = (const float*)d_in[7];
  const float* n2w   = (const float*)d_in[8];
  const float* scw   = (const float*)d_in[9];
  const float* convw = (const float*)d_in[10];
  float* out = (float*)d_out;

  char* ws = (char*)d_ws;
  size_t off = 0;
  unsigned short* emb   = (unsigned short*)(ws+off); off += (size_t)BT*EE*2;      // 33.5 MB
  unsigned short* Wc    = (unsigned short*)(ws+off); off += (size_t)NTOT*EE*2;    // 21 MB
  unsigned short* vlinb = (unsigned short*)(ws+off); off += (size_t)BT*HH*2;      // 67 MB
  float* sumsqp = (float*)(ws+off); off += (size_t)BT*GG*NPART*4;                 // 8.4 MB
  float* dotp   = (float*)(ws+off); off += (size_t)BT*GG*NPART*4;                 // 8.4 MB
  float* vsqp   = (float*)(ws+off); off += (size_t)BT*NPART*4;                    // 2.1 MB
  float* rq     = (float*)(ws+off); off += (size_t)BT*4;
  float* gate   = (float*)(ws+off); off += (size_t)BT*GG*4;
  float* av     = (float*)(ws+off); off += (size_t)BT*GG*4;

  convw_kern<<<(NTOT*EE/4)/256, 256, 0, stream>>>(keyW, valW, Wc);
  gather_kern<<<BT, 256, 0, stream>>>(hids, table, emb);
  rq_kern<<<BT, 256, 0, stream>>>(hs, rq);
  dim3 gg(NTOT/256, BT/256);   // 40 x 64
  gemm8<<<gg, 512, 0, stream>>>(emb, Wc, keyB, valB, n1w, n2w, hs, vlinb, sumsqp, dotp, vsqp);
  scal_kern<<<(BT*GG)/256, 256, 0, stream>>>(sumsqp, dotp, vsqp, rq, gate, av);
  conv_final<<<BT, 256, 0, stream>>>(vlinb, gate, av, convw, scw, out);
}

// Round 4
// 569.593 us; speedup vs baseline: 2.0744x; 1.3701x over previous
//
#include <hip/hip_runtime.h>
#include <hip/hip_bf16.h>

#define BB 4
#define TT 4096
#define HH 2048
#define NHH 16
#define VOC 100000
#define EE 1024
#define GG 4
#define BT (BB*TT)          // 16384 tokens, p = b*TT + t
#define NKEY (GG*HH)        // 8192
#define NTOT (NKEY+HH)      // 10240
#define NPART 32
#define TCV 48              // conv t-chunk (multiple of 3)

static constexpr float EPS_RMS = 1.1920929e-07f;
static constexpr float EPS_SC  = 1e-5f;
static constexpr float INV_SQRT_H = 0.02209708691207961f; // 1/sqrt(2048)

using f32x4 = __attribute__((ext_vector_type(4))) float;
using s8v   = __attribute__((ext_vector_type(8))) short;
using gvoid = __attribute__((address_space(1))) const void;
using lvoid = __attribute__((address_space(3))) void;

__device__ __forceinline__ unsigned short f2bf(float f){
  union { __hip_bfloat16 h; unsigned short u; } cv;
  cv.h = __float2bfloat16(f);
  return cv.u;
}
__device__ __forceinline__ float bf2f(unsigned short u){
  union { float f; unsigned u; } cv;
  cv.u = ((unsigned)u) << 16;
  return cv.f;
}

// ---------------- weight convert: [keyW | valueW] -> bf16 [10240,1024] ----------------
__global__ __launch_bounds__(256) void convw_kern(const float* __restrict__ kW,
    const float* __restrict__ vW, unsigned short* __restrict__ Wc){
  const long idx  = (long)blockIdx.x*256 + threadIdx.x;
  const long base = idx*4;
  const long KN   = (long)NKEY*EE;
  float4 v;
  if (base < KN) v = *(const float4*)(kW + base);
  else           v = *(const float4*)(vW + (base - KN));
  ushort4 o; o.x=f2bf(v.x); o.y=f2bf(v.y); o.z=f2bf(v.z); o.w=f2bf(v.w);
  *(ushort4*)(Wc + base) = o;
}

// ---------------- fused prep: hashed gather -> emb bf16 ; rq[p] ; hsbf [p][h] bf16 ----------------
__global__ __launch_bounds__(256) void prep_kern(const int* __restrict__ hids,
    const float* __restrict__ table, unsigned short* __restrict__ emb,
    const float* __restrict__ hs, float* __restrict__ rq,
    unsigned short* __restrict__ hsbf){
  const int p = blockIdx.x, tid = threadIdx.x;
  // gather
  const int e = tid*4, head = e>>6, d = e&63;
  const long row = (long)hids[p*NHH + head] + (long)head*VOC;
  const float4 v = *(const float4*)(table + row*64 + d);
  ushort4 o; o.x=f2bf(v.x); o.y=f2bf(v.y); o.z=f2bf(v.z); o.w=f2bf(v.w);
  *(ushort4*)(emb + (size_t)p*EE + e) = o;
  // rq + hsbf (p-major bf16 copy of hs)
  const int b = p>>12, t = p&4095;
  const float* hrow = hs + ((size_t)t*BB + b)*HH;
  const int e8 = tid*8;
  float4 v0 = *(const float4*)(hrow+e8);
  float4 v1 = *(const float4*)(hrow+e8+4);
  ushort4 hb0; hb0.x=f2bf(v0.x); hb0.y=f2bf(v0.y); hb0.z=f2bf(v0.z); hb0.w=f2bf(v0.w);
  ushort4 hb1; hb1.x=f2bf(v1.x); hb1.y=f2bf(v1.y); hb1.z=f2bf(v1.z); hb1.w=f2bf(v1.w);
  *(ushort4*)(hsbf + (size_t)p*HH + e8)     = hb0;
  *(ushort4*)(hsbf + (size_t)p*HH + e8 + 4) = hb1;
  float s = v0.x*v0.x+v0.y*v0.y+v0.z*v0.z+v0.w*v0.w
          + v1.x*v1.x+v1.y*v1.y+v1.z*v1.z+v1.w*v1.w;
  #pragma unroll
  for (int of=32;of>=1;of>>=1) s += __shfl_xor(s,of);
  __shared__ float red[4];
  if ((tid&63)==0) red[tid>>6] = s;
  __syncthreads();
  if (tid==0){
    float tot = red[0]+red[1]+red[2]+red[3];
    rq[p] = rsqrtf(tot*(1.0f/HH) + EPS_RMS);
  }
}

// ================= 256x256 8-phase GEMM (T2+T3+T4+T5), fused epilogue =================
__global__ __launch_bounds__(512, 2) void gemm8(
    const unsigned short* __restrict__ A, const unsigned short* __restrict__ Bw,
    const float* __restrict__ key_b, const float* __restrict__ value_b,
    const float* __restrict__ n1w, const float* __restrict__ n2w,
    const unsigned short* __restrict__ hsbf, unsigned short* __restrict__ vlinb,
    float* __restrict__ sumsqp, float* __restrict__ dotp, float* __restrict__ vsqp)
{
  __shared__ unsigned short sh[65536];   // 128 KiB: [2 bufs][A 32KB | B 32KB]
  const int tid = threadIdx.x, w = tid>>6, l = tid&63;
  const int wm = w>>2, wn = w&3;
  const int lg = l&15, lr = l>>4;
  const int tN = blockIdx.x, tM = blockIdx.y;
  const int Mrow0 = tM*256, Nrow0 = tN*256;

  // staging: conflict-free 3-bit chunk swizzle: LDS linear, source chunk = (l&7) ^ (row&7)
  const int lp = l>>3, lcs = (l&7)^lp;
  const size_t aoffT = (size_t)(Mrow0 + w*16 + lp)*EE + lcs*8;
  const size_t boffT = (size_t)(Nrow0 + w*16 + lp)*EE + lcs*8;
  // ds_read: chunk' = (kk*4+lr) ^ (row&7), row&7 == lg&7
  const int c0 = lr ^ (lg&7);
  const unsigned aBase = (unsigned)(wm*8192 + lg*64);
  const unsigned bBase = (unsigned)(16384 + (wn>>1)*8192 + (wn&1)*4096 + lg*64);

  f32x4 acc[8][4] = {};
  s8v aR[2][4], bR[2][4];

#define STAGEH(ISB, H, KT, SB) { \
    const unsigned short* s0_ = ((ISB) ? (Bw + boffT) : (A + aoffT)) + (H)*131072 + (KT)*64; \
    const unsigned d0_ = (SB)*32768 + (ISB)*16384 + (H)*8192 + w*1024; \
    __builtin_amdgcn_global_load_lds((gvoid*)s0_,        (lvoid*)(sh + d0_),       16, 0, 0); \
    __builtin_amdgcn_global_load_lds((gvoid*)(s0_+8192), (lvoid*)(sh + d0_ + 512), 16, 0, 0); \
  }

#define BAR() { asm volatile("" ::: "memory"); __builtin_amdgcn_s_barrier(); asm volatile("" ::: "memory"); }

#define RD_A(CB, KK, MH) { \
    const unsigned short* p_ = sh + (CB)*32768 + aBase; \
    const unsigned ck_ = (unsigned)((c0 ^ ((KK)<<2))<<3); \
    aR[KK][0] = *(const s8v*)(p_ + ((MH)*4+0)*1024 + ck_); \
    aR[KK][1] = *(const s8v*)(p_ + ((MH)*4+1)*1024 + ck_); \
    aR[KK][2] = *(const s8v*)(p_ + ((MH)*4+2)*1024 + ck_); \
    aR[KK][3] = *(const s8v*)(p_ + ((MH)*4+3)*1024 + ck_); }

#define RD_B(CB, KK) { \
    const unsigned short* p_ = sh + (CB)*32768 + bBase; \
    const unsigned ck_ = (unsigned)((c0 ^ ((KK)<<2))<<3); \
    bR[KK][0] = *(const s8v*)(p_ + 0*1024 + ck_); \
    bR[KK][1] = *(const s8v*)(p_ + 1*1024 + ck_); \
    bR[KK][2] = *(const s8v*)(p_ + 2*1024 + ck_); \
    bR[KK][3] = *(const s8v*)(p_ + 3*1024 + ck_); }

#define MM(MH, KK) { \
    __builtin_amdgcn_s_setprio(1); \
    _Pragma("unroll") \
    for (int mf=0; mf<4; mf++) \
      _Pragma("unroll") \
      for (int nf=0; nf<4; nf++) \
        acc[(MH)*4+mf][nf] = __builtin_amdgcn_mfma_f32_16x16x32_bf16(aR[KK][mf], bR[KK][nf], acc[(MH)*4+mf][nf], 0,0,0); \
    __builtin_amdgcn_s_setprio(0); }

// P0: wait current tile's loads (issued 3-4 phases ago -> complete), barrier,
//     then stage first 2 halves of NEXT tile into the buffer just freed.
#define PH0(CB, SB, STKT, DOST) { \
    asm volatile("s_waitcnt vmcnt(0)" ::: "memory"); \
    BAR(); \
    if (DOST) { STAGEH(0, 0, STKT, SB); STAGEH(0, 1, STKT, SB); } \
    RD_A(CB, 0, 0); RD_B(CB, 0); \
    asm volatile("s_waitcnt lgkmcnt(0)" ::: "memory"); \
    __builtin_amdgcn_sched_barrier(0); \
    MM(0, 0); \
    BAR(); }

#define PH1(CB, SB, STKT, DOST) { \
    RD_A(CB, 1, 0); RD_B(CB, 1); \
    if (DOST) { STAGEH(1, 0, STKT, SB); STAGEH(1, 1, STKT, SB); } \
    BAR(); \
    asm volatile("s_waitcnt lgkmcnt(0)" ::: "memory"); \
    __builtin_amdgcn_sched_barrier(0); \
    MM(0, 1); \
    BAR(); }

#define PH2(CB) { \
    RD_A(CB, 0, 1); \
    BAR(); \
    asm volatile("s_waitcnt lgkmcnt(0)" ::: "memory"); \
    __builtin_amdgcn_sched_barrier(0); \
    MM(1, 0); \
    BAR(); }

#define PH3(CB) { \
    RD_A(CB, 1, 1); \
    BAR(); \
    asm volatile("s_waitcnt lgkmcnt(0)" ::: "memory"); \
    __builtin_amdgcn_sched_barrier(0); \
    MM(1, 1); \
    BAR(); }

  // prologue: stage K-tile 0 (4 half-tiles) into buf0
  STAGEH(0,0,0,0); STAGEH(0,1,0,0); STAGEH(1,0,0,0); STAGEH(1,1,0,0);

  #pragma unroll 1
  for (int i=0; i<8; i++){
    const int kt = 2*i;
    PH0(0, 1, kt+1, true);
    PH1(0, 1, kt+1, true);
    PH2(0);
    PH3(0);
    PH0(1, 0, kt+2, (kt+2)<16);
    PH1(1, 0, kt+2, (kt+2)<16);
    PH2(1);
    PH3(1);
  }

#undef STAGEH
#undef BAR
#undef RD_A
#undef RD_B
#undef MM
#undef PH0
#undef PH1
#undef PH2
#undef PH3

  // ---- epilogue ----
  const bool isK = (Nrow0 < NKEY);
  float bias[4], cw[4];
  #pragma unroll
  for (int nf=0; nf<4; nf++){
    const int n = Nrow0 + wn*64 + nf*16 + lg;
    if (isK){ bias[nf] = key_b[n]; cw[nf] = n1w[n]*n2w[n]; }
    else    { bias[nf] = value_b[n-NKEY]; cw[nf] = 0.f; }
  }

  if (isK){
    // stage hsbf tile [256 p-rows][256 cols] bf16 into LDS (128 KB), XOR-swizzled:
    // element (r,c) stored at c ^ (((r>>2)&3)<<4)
    unsigned short* hsT = sh;
    const int colbase = Nrow0 & (HH-1);
    #pragma unroll
    for (int pass=0; pass<16; pass++){
      const int r = pass*16 + (tid>>5);
      const int c8 = (tid&31)*8;
      const int p = Mrow0 + r;
      s8v wv = *(const s8v*)(hsbf + (size_t)p*HH + colbase + c8);
      *(s8v*)(hsT + r*256 + (c8 ^ (((r>>2)&3)<<4))) = wv;
    }
    __syncthreads();
    const int g = Nrow0 >> 11;
    const int slot = (tN&7)*4 + wn;
    #pragma unroll
    for (int mfa=0; mfa<8; mfa++){
      #pragma unroll
      for (int rr=0; rr<4; rr++){
        const int rowl = wm*128 + mfa*16 + lr*4 + rr;   // (rowl>>2)&3 == lr
        const int p = Mrow0 + rowl;
        float ssq=0.f, dt=0.f;
        #pragma unroll
        for (int nf=0; nf<4; nf++){
          const float c = acc[mfa][nf][rr] + bias[nf];
          const float hv = bf2f(hsT[rowl*256 + wn*64 + (((nf^lr))<<4) + lg]);
          ssq += c*c;
          dt  += c * cw[nf] * hv;
        }
        #pragma unroll
        for (int o=1;o<16;o<<=1){ ssq += __shfl_xor(ssq,o); dt += __shfl_xor(dt,o); }
        if (lg==0){
          sumsqp[(size_t)(p*GG+g)*NPART + slot] = ssq;
          dotp  [(size_t)(p*GG+g)*NPART + slot] = dt;
        }
      }
    }
  } else {
    const int slot = (tN-32)*4 + wn;
    const int h0 = Nrow0 - NKEY + wn*64;
    const int pbase = Mrow0 + wm*128;
    #pragma unroll
    for (int mfa=0; mfa<8; mfa++){
      #pragma unroll
      for (int rr=0; rr<4; rr++){
        const int p = pbase + mfa*16 + lr*4 + rr;
        float ssq=0.f;
        #pragma unroll
        for (int nf=0; nf<4; nf++){
          const float c = acc[mfa][nf][rr] + bias[nf];
          vlinb[(size_t)p*HH + h0 + nf*16 + lg] = f2bf(c);
          ssq += c*c;
        }
        #pragma unroll
        for (int o=1;o<16;o<<=1){ ssq += __shfl_xor(ssq,o); }
        if (lg==0) vsqp[(size_t)p*NPART + slot] = ssq;
      }
    }
  }
}

// ---------------- per-(token,group) scalars: gate + xn-scale a ----------------
__global__ __launch_bounds__(256) void scal_kern(const float* __restrict__ sumsqp,
    const float* __restrict__ dotp, const float* __restrict__ vsqp,
    const float* __restrict__ rq, float* __restrict__ gate, float* __restrict__ av){
  const int i = blockIdx.x*256 + threadIdx.x;   // BT*GG
  const int p = i>>2;
  float ss=0.f, dd=0.f, vv=0.f;
  #pragma unroll
  for (int j=0;j<NPART;j++){ ss += sumsqp[(size_t)i*NPART+j]; dd += dotp[(size_t)i*NPART+j]; }
  #pragma unroll
  for (int j=0;j<NPART;j++){ vv += vsqp[(size_t)p*NPART+j]; }
  const float rk = rsqrtf(ss*(1.0f/HH) + EPS_RMS);
  const float gv = rk * rq[p] * dd * INV_SQRT_H;
  const float sgn = (gv>0.f)?1.f:((gv<0.f)?-1.f:0.f);
  const float g1 = sqrtf(fmaxf(fabsf(gv),1e-6f))*sgn;
  const float gt = 1.f/(1.f+__expf(-g1));
  const float msvl = vv*(1.0f/HH);
  const float a = gt * rsqrtf(gt*gt*msvl + EPS_SC);
  gate[i]=gt; av[i]=a;
}

// ---------------- conv: residue-mod-3 register window, weights loaded once ----------------
__device__ __forceinline__ ushort4 ldrow(const unsigned short* __restrict__ v, int b, int t, int h0){
  if (t < 0){ ushort4 z; z.x=0;z.y=0;z.z=0;z.w=0; return z; }
  return *(const ushort4*)(v + (size_t)((b<<12)|t)*HH + h0);
}
__device__ __forceinline__ void ldav(const float* __restrict__ av, int b, int t, float* a){
  if (t < 0){ a[0]=0.f;a[1]=0.f;a[2]=0.f;a[3]=0.f; }
  else { const float4 x = *(const float4*)(av + (size_t)((b<<12)|t)*GG);
         a[0]=x.x;a[1]=x.y;a[2]=x.z;a[3]=x.w; }
}

__global__ __launch_bounds__(256) void conv2_kern(const unsigned short* __restrict__ vlinb,
    const float* __restrict__ gate, const float* __restrict__ av,
    const float* __restrict__ conv_w, const float* __restrict__ scw,
    float* __restrict__ out){
  const int bx = blockIdx.x;          // chunk*2 + hb
  const int b  = blockIdx.y;
  const int t0 = (bx>>1)*TCV;
  const int h0 = (bx&1)*1024 + threadIdx.x*4;

  float cwv[4][4][4];   // [g][h-sub][tap]
  float sc4[4][4];      // [g][h-sub]
  #pragma unroll
  for (int g=0; g<4; g++){
    #pragma unroll
    for (int j2=0; j2<4; j2++){
      const int c = g*HH + h0 + j2;
      const float4 wv = *(const float4*)(conv_w + (size_t)c*4);
      cwv[g][j2][0]=wv.x; cwv[g][j2][1]=wv.y; cwv[g][j2][2]=wv.z; cwv[g][j2][3]=wv.w;
      sc4[g][j2] = scw[c];
    }
  }

  #pragma unroll 1
  for (int r=0; r<3; r++){
    const int tf = t0 + r;
    ushort4 w0 = ldrow(vlinb, b, tf-9, h0);
    ushort4 w1 = ldrow(vlinb, b, tf-6, h0);
    ushort4 w2 = ldrow(vlinb, b, tf-3, h0);
    ushort4 w3; w3.x=0;w3.y=0;w3.z=0;w3.w=0;
    #pragma unroll
    for (int j=0; j<16; j++){
      const int t = tf + 3*j;
      if (t < TT){
        const int p = (b<<12)|t;
        w3 = *(const ushort4*)(vlinb + (size_t)p*HH + h0);
        float a0[4],a1[4],a2[4],a3[4];
        ldav(av, b, t-9, a0); ldav(av, b, t-6, a1); ldav(av, b, t-3, a2); ldav(av, b, t, a3);
        float gt4[4];
        { const float4 x = *(const float4*)(gate + (size_t)p*GG);
          gt4[0]=x.x; gt4[1]=x.y; gt4[2]=x.z; gt4[3]=x.w; }
        float v0[4],v1[4],v2[4],v3[4];
        v0[0]=bf2f(w0.x); v0[1]=bf2f(w0.y); v0[2]=bf2f(w0.z); v0[3]=bf2f(w0.w);
        v1[0]=bf2f(w1.x); v1[1]=bf2f(w1.y); v1[2]=bf2f(w1.z); v1[3]=bf2f(w1.w);
        v2[0]=bf2f(w2.x); v2[1]=bf2f(w2.y); v2[2]=bf2f(w2.z); v2[3]=bf2f(w2.w);
        v3[0]=bf2f(w3.x); v3[1]=bf2f(w3.y); v3[2]=bf2f(w3.z); v3[3]=bf2f(w3.w);
        float4 ov;
        float res[4];
        #pragma unroll
        for (int j2=0; j2<4; j2++){
          float acc = 0.f;
          #pragma unroll
          for (int g=0; g<4; g++){
            float y = cwv[g][j2][0]*a0[g]*v0[j2]
                    + cwv[g][j2][1]*a1[g]*v1[j2]
                    + cwv[g][j2][2]*a2[g]*v2[j2]
                    + cwv[g][j2][3]*a3[g]*v3[j2];
            y *= sc4[g][j2];
            const float sy = y * (1.f/(1.f+__expf(-y)));
            acc += gt4[g]*v3[j2] + sy;
          }
          res[j2] = acc*0.25f;
        }
        ov.x=res[0]; ov.y=res[1]; ov.z=res[2]; ov.w=res[3];
        *(float4*)(out + ((size_t)t*BB + b)*HH + h0) = ov;
      }
      w0=w1; w1=w2; w2=w3;
    }
  }
}

extern "C" void kernel_launch(void* const* d_in, const int* in_sizes, int n_in,
                              void* d_out, int out_size, void* d_ws, size_t ws_size,
                              hipStream_t stream){
  (void)in_sizes; (void)n_in; (void)out_size; (void)ws_size;
  const float* hs    = (const float*)d_in[0];
  const int*   hids  = (const int*)d_in[1];
  const float* table = (const float*)d_in[2];
  const float* keyW  = (const float*)d_in[3];
  const float* keyB  = (const float*)d_in[4];
  const float* valW  = (const float*)d_in[5];
  const float* valB  = (const float*)d_in[6];
  const float* n1w   = (const float*)d_in[7];
  const float* n2w   = (const float*)d_in[8];
  const float* scw   = (const float*)d_in[9];
  const float* convw = (const float*)d_in[10];
  float* out = (float*)d_out;

  char* ws = (char*)d_ws;
  size_t off = 0;
  unsigned short* emb   = (unsigned short*)(ws+off); off += (size_t)BT*EE*2;      // 33.5 MB
  unsigned short* Wc    = (unsigned short*)(ws+off); off += (size_t)NTOT*EE*2;    // 21 MB
  unsigned short* vlinb = (unsigned short*)(ws+off); off += (size_t)BT*HH*2;      // 67 MB
  unsigned short* hsbf  = (unsigned short*)(ws+off); off += (size_t)BT*HH*2;      // 67 MB
  float* sumsqp = (float*)(ws+off); off += (size_t)BT*GG*NPART*4;                 // 8.4 MB
  float* dotp   = (float*)(ws+off); off += (size_t)BT*GG*NPART*4;                 // 8.4 MB
  float* vsqp   = (float*)(ws+off); off += (size_t)BT*NPART*4;                    // 2.1 MB
  float* rq     = (float*)(ws+off); off += (size_t)BT*4;
  float* gate   = (float*)(ws+off); off += (size_t)BT*GG*4;
  float* av     = (float*)(ws+off); off += (size_t)BT*GG*4;

  convw_kern<<<(NTOT*EE/4)/256, 256, 0, stream>>>(keyW, valW, Wc);
  prep_kern<<<BT, 256, 0, stream>>>(hids, table, emb, hs, rq, hsbf);
  dim3 gg(NTOT/256, BT/256);   // 40 x 64
  gemm8<<<gg, 512, 0, stream>>>(emb, Wc, keyB, valB, n1w, n2w, hsbf, vlinb, sumsqp, dotp, vsqp);
  scal_kern<<<(BT*GG)/256, 256, 0, stream>>>(sumsqp, dotp, vsqp, rq, gate, av);
  dim3 cg(((TT + TCV - 1)/TCV)*2, BB);  // 172 x 4
  conv2_kern<<<cg, 256, 0, stream>>>(vlinb, gate, av, convw, scw, out);
}

// Round 5
// 554.457 us; speedup vs baseline: 2.1311x; 1.0273x over previous
//
#include <hip/hip_runtime.h>
#include <hip/hip_bf16.h>

#define BB 4
#define TT 4096
#define HH 2048
#define NHH 16
#define VOC 100000
#define EE 1024
#define GG 4
#define BT (BB*TT)          // 16384 tokens, p = b*TT + t
#define NKEY (GG*HH)        // 8192
#define NTOT (NKEY+HH)      // 10240
#define NPART 32
#define TCV 48              // conv t-chunk (multiple of 3)

static constexpr float EPS_RMS = 1.1920929e-07f;
static constexpr float EPS_SC  = 1e-5f;
static constexpr float INV_SQRT_H = 0.02209708691207961f; // 1/sqrt(2048)

using f32x4 = __attribute__((ext_vector_type(4))) float;
using f32x2 = __attribute__((ext_vector_type(2))) float;
using s8v   = __attribute__((ext_vector_type(8))) short;
using gvoid = __attribute__((address_space(1))) const void;
using lvoid = __attribute__((address_space(3))) void;

__device__ __forceinline__ unsigned short f2bf(float f){
  union { __hip_bfloat16 h; unsigned short u; } cv;
  cv.h = __float2bfloat16(f);
  return cv.u;
}
__device__ __forceinline__ float bf2f(unsigned short u){
  union { float f; unsigned u; } cv;
  cv.u = ((unsigned)u) << 16;
  return cv.f;
}

// ---------------- weight convert: [keyW | valueW] -> bf16 [10240,1024] ----------------
__global__ __launch_bounds__(256) void convw_kern(const float* __restrict__ kW,
    const float* __restrict__ vW, unsigned short* __restrict__ Wc){
  const long idx  = (long)blockIdx.x*256 + threadIdx.x;
  const long base = idx*4;
  const long KN   = (long)NKEY*EE;
  float4 v;
  if (base < KN) v = *(const float4*)(kW + base);
  else           v = *(const float4*)(vW + (base - KN));
  ushort4 o; o.x=f2bf(v.x); o.y=f2bf(v.y); o.z=f2bf(v.z); o.w=f2bf(v.w);
  *(ushort4*)(Wc + base) = o;
}

// ---------------- fused prep: hashed gather -> emb bf16 ; rq[p] ; hsbf [p][h] bf16 ----------------
__global__ __launch_bounds__(256) void prep_kern(const int* __restrict__ hids,
    const float* __restrict__ table, unsigned short* __restrict__ emb,
    const float* __restrict__ hs, float* __restrict__ rq,
    unsigned short* __restrict__ hsbf){
  const int p = blockIdx.x, tid = threadIdx.x;
  const int e = tid*4, head = e>>6, d = e&63;
  const long row = (long)hids[p*NHH + head] + (long)head*VOC;
  const float4 v = *(const float4*)(table + row*64 + d);
  ushort4 o; o.x=f2bf(v.x); o.y=f2bf(v.y); o.z=f2bf(v.z); o.w=f2bf(v.w);
  *(ushort4*)(emb + (size_t)p*EE + e) = o;
  const int b = p>>12, t = p&4095;
  const float* hrow = hs + ((size_t)t*BB + b)*HH;
  const int e8 = tid*8;
  float4 v0 = *(const float4*)(hrow+e8);
  float4 v1 = *(const float4*)(hrow+e8+4);
  ushort4 hb0; hb0.x=f2bf(v0.x); hb0.y=f2bf(v0.y); hb0.z=f2bf(v0.z); hb0.w=f2bf(v0.w);
  ushort4 hb1; hb1.x=f2bf(v1.x); hb1.y=f2bf(v1.y); hb1.z=f2bf(v1.z); hb1.w=f2bf(v1.w);
  *(ushort4*)(hsbf + (size_t)p*HH + e8)     = hb0;
  *(ushort4*)(hsbf + (size_t)p*HH + e8 + 4) = hb1;
  float s = v0.x*v0.x+v0.y*v0.y+v0.z*v0.z+v0.w*v0.w
          + v1.x*v1.x+v1.y*v1.y+v1.z*v1.z+v1.w*v1.w;
  #pragma unroll
  for (int of=32;of>=1;of>>=1) s += __shfl_xor(s,of);
  __shared__ float red[4];
  if ((tid&63)==0) red[tid>>6] = s;
  __syncthreads();
  if (tid==0){
    float tot = red[0]+red[1]+red[2]+red[3];
    rq[p] = rsqrtf(tot*(1.0f/HH) + EPS_RMS);
  }
}

// ======== 256x256 GEMM, reg-pipelined quadrants, 2 barriers/K-tile, fused epilogue ========
__global__ __launch_bounds__(512, 2) void gemm8(
    const unsigned short* __restrict__ A, const unsigned short* __restrict__ Bw,
    const float* __restrict__ key_b, const float* __restrict__ value_b,
    const float* __restrict__ n1w, const float* __restrict__ n2w,
    const unsigned short* __restrict__ hsbf, unsigned short* __restrict__ vlinb,
    f32x2* __restrict__ sdp, float* __restrict__ vsqp)
{
  __shared__ unsigned short sh[65536];   // 128 KiB: [2 bufs][A 32KB | B 32KB]
  const int tid = threadIdx.x, w = tid>>6, l = tid&63;
  const int wm = w>>2, wn = w&3;
  const int lg = l&15, lr = l>>4;
  // XCD-aware bijective swizzle: 2560 blocks, 8 XCDs, 320/XCD = 8 contiguous tM rows
  const int wg  = blockIdx.x;
  const int swz = (wg&7)*320 + (wg>>3);
  const int tM  = swz/40, tN = swz - tM*40;
  const int Mrow0 = tM*256, Nrow0 = tN*256;

  // staging: conflict-free 3-bit chunk swizzle: LDS linear, source chunk = (l&7) ^ (row&7)
  const int lp = l>>3, lcs = (l&7)^lp;
  const size_t aoffT = (size_t)(Mrow0 + w*16 + lp)*EE + lcs*8;
  const size_t boffT = (size_t)(Nrow0 + w*16 + lp)*EE + lcs*8;
  // ds_read: chunk' = (kk*4+lr) ^ (row&7), row&7 == lg&7
  const int c0 = lr ^ (lg&7);
  const unsigned aBase = (unsigned)(wm*8192 + lg*64);
  const unsigned bBase = (unsigned)(16384 + (wn>>1)*8192 + (wn&1)*4096 + lg*64);

  f32x4 acc[8][4] = {};
  s8v aR0[4], aR1[4], bR0[4], bR1[4];

#define STAGEH(ISB, H, KT, SB) { \
    const unsigned short* s0_ = ((ISB) ? (Bw + boffT) : (A + aoffT)) + (H)*131072 + (KT)*64; \
    const unsigned d0_ = (SB)*32768 + (ISB)*16384 + (H)*8192 + w*1024; \
    __builtin_amdgcn_global_load_lds((gvoid*)s0_,        (lvoid*)(sh + d0_),       16, 0, 0); \
    __builtin_amdgcn_global_load_lds((gvoid*)(s0_+8192), (lvoid*)(sh + d0_ + 512), 16, 0, 0); \
  }
#define STAGE4(KT, SB) { STAGEH(0,0,KT,SB); STAGEH(0,1,KT,SB); STAGEH(1,0,KT,SB); STAGEH(1,1,KT,SB); }

#define BAR() { asm volatile("" ::: "memory"); __builtin_amdgcn_s_barrier(); asm volatile("" ::: "memory"); }

#define RD_A(CB, KK, MH, DST) { \
    const unsigned short* p_ = sh + (CB)*32768 + aBase; \
    const unsigned ck_ = (unsigned)((c0 ^ ((KK)<<2))<<3); \
    DST[0] = *(const s8v*)(p_ + ((MH)*4+0)*1024 + ck_); \
    DST[1] = *(const s8v*)(p_ + ((MH)*4+1)*1024 + ck_); \
    DST[2] = *(const s8v*)(p_ + ((MH)*4+2)*1024 + ck_); \
    DST[3] = *(const s8v*)(p_ + ((MH)*4+3)*1024 + ck_); }

#define RD_B(CB, KK, DST) { \
    const unsigned short* p_ = sh + (CB)*32768 + bBase; \
    const unsigned ck_ = (unsigned)((c0 ^ ((KK)<<2))<<3); \
    DST[0] = *(const s8v*)(p_ + 0*1024 + ck_); \
    DST[1] = *(const s8v*)(p_ + 1*1024 + ck_); \
    DST[2] = *(const s8v*)(p_ + 2*1024 + ck_); \
    DST[3] = *(const s8v*)(p_ + 3*1024 + ck_); }

#define MM(MH, AF, BF) { \
    __builtin_amdgcn_s_setprio(1); \
    _Pragma("unroll") \
    for (int mf=0; mf<4; mf++) \
      _Pragma("unroll") \
      for (int nf=0; nf<4; nf++) \
        acc[(MH)*4+mf][nf] = __builtin_amdgcn_mfma_f32_16x16x32_bf16(AF[mf], BF[nf], acc[(MH)*4+mf][nf], 0,0,0); \
    __builtin_amdgcn_s_setprio(0); }

// One K-tile: quadrants q(MH,KK) in order (0,0),(0,1),(1,0),(1,1); ds_reads for
// quadrant q+1 issued before MFMA of q (register WAR enforces the pipeline);
// 2 barriers per tile; counted-by-construction vmcnt(0) 3 phases after issue.
#define TILE(CB, NB, KT1, DOST) { \
    BAR(); \
    if (DOST) STAGE4(KT1, NB); \
    RD_A(CB,1,0,aR1); RD_B(CB,1,bR1); \
    MM(0, aR0, bR0); \
    RD_A(CB,0,1,aR0); \
    MM(0, aR1, bR1); \
    RD_A(CB,1,1,aR1); \
    MM(1, aR0, bR0); \
    asm volatile("s_waitcnt vmcnt(0)" ::: "memory"); \
    BAR(); \
    RD_A(NB,0,0,aR0); RD_B(NB,0,bR0); \
    MM(1, aR1, bR1); }

#define TILE_LAST(CB) { \
    BAR(); \
    RD_A(CB,1,0,aR1); RD_B(CB,1,bR1); \
    MM(0, aR0, bR0); \
    RD_A(CB,0,1,aR0); \
    MM(0, aR1, bR1); \
    RD_A(CB,1,1,aR1); \
    MM(1, aR0, bR0); \
    MM(1, aR1, bR1); }

  // prologue: stage K-tile 0 into buf0, load q0 fragments
  STAGE4(0, 0);
  asm volatile("s_waitcnt vmcnt(0)" ::: "memory");
  BAR();
  RD_A(0,0,0,aR0); RD_B(0,0,bR0);

  #pragma unroll 1
  for (int i=0; i<7; i++){
    const int kt = 2*i;
    TILE(0, 1, kt+1, true);
    TILE(1, 0, kt+2, true);
  }
  TILE(0, 1, 15, true);   // tile 14, stages tile 15
  TILE_LAST(1);           // tile 15

#undef STAGEH
#undef STAGE4
#undef RD_A
#undef RD_B
#undef MM
#undef TILE
#undef TILE_LAST

  BAR();  // all waves done reading LDS tile buffers before epilogue reuses LDS

  // ---- epilogue ----
  const bool isK = (Nrow0 < NKEY);
  float bias[4], cw[4]; int hcol[4];
  #pragma unroll
  for (int nf=0; nf<4; nf++){
    const int n = Nrow0 + wn*64 + nf*16 + lg;
    hcol[nf] = n & (HH-1);
    if (isK){ bias[nf] = key_b[n]; cw[nf] = n1w[n]*n2w[n]; }
    else    { bias[nf] = value_b[n-NKEY]; cw[nf] = 0.f; }
  }

  if (isK){
    const int g = Nrow0 >> 11;
    const int slot = (tN&7)*4 + wn;
    char* wreg = (char*)sh + w*16384;   // 16 KB private region per wave
    // write per-lane partials: [row 0..127][lg 0..15] float2 (ssq, dt), chunk-XOR swizzled
    #pragma unroll
    for (int mfa=0; mfa<8; mfa++){
      #pragma unroll
      for (int rr=0; rr<4; rr++){
        const int rowl = mfa*16 + lr*4 + rr;
        const int p = Mrow0 + wm*128 + rowl;
        const unsigned short* hrow = hsbf + (size_t)p*HH;
        float ssq=0.f, dt=0.f;
        #pragma unroll
        for (int nf=0; nf<4; nf++){
          const float c = acc[mfa][nf][rr] + bias[nf];
          ssq += c*c;
          dt  += c * cw[nf] * bf2f(hrow[hcol[nf]]);
        }
        f32x2 pr; pr[0]=ssq; pr[1]=dt;
        *(f32x2*)(wreg + rowl*128 + (((lg>>1) ^ (rowl&7))<<4) + ((lg&1)<<3)) = pr;
      }
    }
    // wave-private read-back: lane l sums rows l and l+64 across 16 lg slots
    #pragma unroll
    for (int rh=0; rh<2; rh++){
      const int r = l + rh*64;
      float ssq=0.f, dt=0.f;
      #pragma unroll
      for (int c=0; c<8; c++){
        f32x4 v = *(const f32x4*)(wreg + r*128 + ((c ^ (r&7))<<4));
        ssq += v[0] + v[2]; dt += v[1] + v[3];
      }
      const int p = Mrow0 + wm*128 + r;
      f32x2 o; o[0]=ssq; o[1]=dt;
      sdp[(size_t)(p*GG+g)*NPART + slot] = o;
    }
  } else {
    const int slot = (tN-32)*4 + wn;
    const int h0 = Nrow0 - NKEY + wn*64;
    const int pbase = Mrow0 + wm*128;
    #pragma unroll
    for (int mfa=0; mfa<8; mfa++){
      #pragma unroll
      for (int rr=0; rr<4; rr++){
        const int p = pbase + mfa*16 + lr*4 + rr;
        float ssq=0.f;
        #pragma unroll
        for (int nf=0; nf<4; nf++){
          const float c = acc[mfa][nf][rr] + bias[nf];
          vlinb[(size_t)p*HH + h0 + nf*16 + lg] = f2bf(c);
          ssq += c*c;
        }
        #pragma unroll
        for (int o=1;o<16;o<<=1){ ssq += __shfl_xor(ssq,o); }
        if (lg==0) vsqp[(size_t)p*NPART + slot] = ssq;
      }
    }
  }
}

// ---------------- per-(token,group) scalars: gate + xn-scale a ----------------
__global__ __launch_bounds__(256) void scal_kern(const f32x2* __restrict__ sdp,
    const float* __restrict__ vsqp,
    const float* __restrict__ rq, float* __restrict__ gate, float* __restrict__ av){
  const int i = blockIdx.x*256 + threadIdx.x;   // BT*GG
  const int p = i>>2;
  float ss=0.f, dd=0.f, vv=0.f;
  const f32x2* sp = sdp + (size_t)i*NPART;
  #pragma unroll
  for (int j=0;j<NPART;j++){ f32x2 v = sp[j]; ss += v[0]; dd += v[1]; }
  #pragma unroll
  for (int j=0;j<NPART;j++){ vv += vsqp[(size_t)p*NPART+j]; }
  const float rk = rsqrtf(ss*(1.0f/HH) + EPS_RMS);
  const float gv = rk * rq[p] * dd * INV_SQRT_H;
  const float sgn = (gv>0.f)?1.f:((gv<0.f)?-1.f:0.f);
  const float g1 = sqrtf(fmaxf(fabsf(gv),1e-6f))*sgn;
  const float gt = 1.f/(1.f+__expf(-g1));
  const float msvl = vv*(1.0f/HH);
  const float a = gt * rsqrtf(gt*gt*msvl + EPS_SC);
  gate[i]=gt; av[i]=a;
}

// ---------------- conv: residue-mod-3 register window, weights loaded once ----------------
__device__ __forceinline__ ushort4 ldrow(const unsigned short* __restrict__ v, int b, int t, int h0){
  if (t < 0){ ushort4 z; z.x=0;z.y=0;z.z=0;z.w=0; return z; }
  return *(const ushort4*)(v + (size_t)((b<<12)|t)*HH + h0);
}
__device__ __forceinline__ void ldav(const float* __restrict__ av, int b, int t, float* a){
  if (t < 0){ a[0]=0.f;a[1]=0.f;a[2]=0.f;a[3]=0.f; }
  else { const float4 x = *(const float4*)(av + (size_t)((b<<12)|t)*GG);
         a[0]=x.x;a[1]=x.y;a[2]=x.z;a[3]=x.w; }
}

__global__ __launch_bounds__(256) void conv2_kern(const unsigned short* __restrict__ vlinb,
    const float* __restrict__ gate, const float* __restrict__ av,
    const float* __restrict__ conv_w, const float* __restrict__ scw,
    float* __restrict__ out){
  const int bx = blockIdx.x;          // chunk*2 + hb
  const int b  = blockIdx.y;
  const int t0 = (bx>>1)*TCV;
  const int h0 = (bx&1)*1024 + threadIdx.x*4;

  float cwv[4][4][4];   // [g][h-sub][tap]
  float sc4[4][4];      // [g][h-sub]
  #pragma unroll
  for (int g=0; g<4; g++){
    #pragma unroll
    for (int j2=0; j2<4; j2++){
      const int c = g*HH + h0 + j2;
      const float4 wv = *(const float4*)(conv_w + (size_t)c*4);
      cwv[g][j2][0]=wv.x; cwv[g][j2][1]=wv.y; cwv[g][j2][2]=wv.z; cwv[g][j2][3]=wv.w;
      sc4[g][j2] = scw[c];
    }
  }

  #pragma unroll 1
  for (int r=0; r<3; r++){
    const int tf = t0 + r;
    ushort4 w0 = ldrow(vlinb, b, tf-9, h0);
    ushort4 w1 = ldrow(vlinb, b, tf-6, h0);
    ushort4 w2 = ldrow(vlinb, b, tf-3, h0);
    ushort4 w3; w3.x=0;w3.y=0;w3.z=0;w3.w=0;
    #pragma unroll
    for (int j=0; j<16; j++){
      const int t = tf + 3*j;
      if (t < TT){
        const int p = (b<<12)|t;
        w3 = *(const ushort4*)(vlinb + (size_t)p*HH + h0);
        float a0[4],a1[4],a2[4],a3[4];
        ldav(av, b, t-9, a0); ldav(av, b, t-6, a1); ldav(av, b, t-3, a2); ldav(av, b, t, a3);
        float gt4[4];
        { const float4 x = *(const float4*)(gate + (size_t)p*GG);
          gt4[0]=x.x; gt4[1]=x.y; gt4[2]=x.z; gt4[3]=x.w; }
        float v0[4],v1[4],v2[4],v3[4];
        v0[0]=bf2f(w0.x); v0[1]=bf2f(w0.y); v0[2]=bf2f(w0.z); v0[3]=bf2f(w0.w);
        v1[0]=bf2f(w1.x); v1[1]=bf2f(w1.y); v1[2]=bf2f(w1.z); v1[3]=bf2f(w1.w);
        v2[0]=bf2f(w2.x); v2[1]=bf2f(w2.y); v2[2]=bf2f(w2.z); v2[3]=bf2f(w2.w);
        v3[0]=bf2f(w3.x); v3[1]=bf2f(w3.y); v3[2]=bf2f(w3.z); v3[3]=bf2f(w3.w);
        float4 ov;
        float res[4];
        #pragma unroll
        for (int j2=0; j2<4; j2++){
          float acc = 0.f;
          #pragma unroll
          for (int g=0; g<4; g++){
            float y = cwv[g][j2][0]*a0[g]*v0[j2]
                    + cwv[g][j2][1]*a1[g]*v1[j2]
                    + cwv[g][j2][2]*a2[g]*v2[j2]
                    + cwv[g][j2][3]*a3[g]*v3[j2];
            y *= sc4[g][j2];
            const float sy = y * (1.f/(1.f+__expf(-y)));
            acc += gt4[g]*v3[j2] + sy;
          }
          res[j2] = acc*0.25f;
        }
        ov.x=res[0]; ov.y=res[1]; ov.z=res[2]; ov.w=res[3];
        *(float4*)(out + ((size_t)t*BB + b)*HH + h0) = ov;
      }
      w0=w1; w1=w2; w2=w3;
    }
  }
}

extern "C" void kernel_launch(void* const* d_in, const int* in_sizes, int n_in,
                              void* d_out, int out_size, void* d_ws, size_t ws_size,
                              hipStream_t stream){
  (void)in_sizes; (void)n_in; (void)out_size; (void)ws_size;
  const float* hs    = (const float*)d_in[0];
  const int*   hids  = (const int*)d_in[1];
  const float* table = (const float*)d_in[2];
  const float* keyW  = (const float*)d_in[3];
  const float* keyB  = (const float*)d_in[4];
  const float* valW  = (const float*)d_in[5];
  const float* valB  = (const float*)d_in[6];
  const float* n1w   = (const float*)d_in[7];
  const float* n2w   = (const float*)d_in[8];
  const float* scw   = (const float*)d_in[9];
  const float* convw = (const float*)d_in[10];
  float* out = (float*)d_out;

  char* ws = (char*)d_ws;
  size_t off = 0;
  unsigned short* emb   = (unsigned short*)(ws+off); off += (size_t)BT*EE*2;      // 33.5 MB
  unsigned short* Wc    = (unsigned short*)(ws+off); off += (size_t)NTOT*EE*2;    // 21 MB
  unsigned short* vlinb = (unsigned short*)(ws+off); off += (size_t)BT*HH*2;      // 67 MB
  unsigned short* hsbf  = (unsigned short*)(ws+off); off += (size_t)BT*HH*2;      // 67 MB
  f32x2* sdp    = (f32x2*)(ws+off); off += (size_t)BT*GG*NPART*8;                 // 16.8 MB
  float* vsqp   = (float*)(ws+off); off += (size_t)BT*NPART*4;                    // 2.1 MB
  float* rq     = (float*)(ws+off); off += (size_t)BT*4;
  float* gate   = (float*)(ws+off); off += (size_t)BT*GG*4;
  float* av     = (float*)(ws+off); off += (size_t)BT*GG*4;

  convw_kern<<<(NTOT*EE/4)/256, 256, 0, stream>>>(keyW, valW, Wc);
  prep_kern<<<BT, 256, 0, stream>>>(hids, table, emb, hs, rq, hsbf);
  gemm8<<<2560, 512, 0, stream>>>(emb, Wc, keyB, valB, n1w, n2w, hsbf, vlinb, sdp, vsqp);
  scal_kern<<<(BT*GG)/256, 256, 0, stream>>>(sdp, vsqp, rq, gate, av);
  dim3 cg(((TT + TCV - 1)/TCV)*2, BB);  // 172 x 4
  conv2_kern<<<cg, 256, 0, stream>>>(vlinb, gate, av, convw, scw, out);
}